// Round 10
// baseline (4922.050 us; speedup 1.0000x reference)
//
#include <hip/hip_runtime.h>
#include <hip/hip_bf16.h>
#include <cmath>

typedef __attribute__((ext_vector_type(8))) short short8;
typedef __attribute__((ext_vector_type(4))) short short4_t;
typedef __attribute__((ext_vector_type(4))) float float4_t;

__device__ __forceinline__ float bf2f(unsigned short u) {
    union { unsigned int i; float f; } v; v.i = ((unsigned int)u) << 16; return v.f;
}
__device__ __forceinline__ unsigned short f2bf(float f) {
    union { float f; unsigned int i; } v; v.f = f;
    unsigned int r = v.i + 0x7FFF + ((v.i >> 16) & 1);  // round-to-nearest-even
    return (unsigned short)(r >> 16);
}
__device__ __forceinline__ float sigm(float x) { return 1.f / (1.f + __expf(-x)); }
__device__ __forceinline__ float tanh_fast(float x) {
    float e = __expf(2.f * x);
    return 1.f - 2.f / (e + 1.f);
}

// coherence-point (IC) ops: bypass non-coherent L1/L2 on both sides
__device__ __forceinline__ void st_b16_coh(unsigned short* p, unsigned short v) {
    asm volatile("global_store_short %0, %1, off sc0 sc1" :: "v"(p), "v"((unsigned int)v) : "memory");
}
__device__ __forceinline__ float4_t ld_b128_coh_raw(const unsigned short* p) {
    float4_t v;
    asm volatile("global_load_dwordx4 %0, %1, off sc0 sc1" : "=v"(v) : "v"(p));
    return v;  // NOT READY until s_waitcnt vmcnt(0)
}

__device__ __forceinline__ short8 ld_frag8(const unsigned short* p) {
    short4_t a = *reinterpret_cast<const short4_t*>(p);
    short4_t b = *reinterpret_cast<const short4_t*>(p + 4);
    short8 v;
    v[0]=a[0]; v[1]=a[1]; v[2]=a[2]; v[3]=a[3];
    v[4]=b[0]; v[5]=b[1]; v[6]=b[2]; v[7]=b[3];
    return v;
}

// ---------------- prep kernels ----------------

// in: fp32 [R][C]  ->  out: bf16 [C][R]
__global__ void k_transpose_bf16(const float* __restrict__ in, unsigned short* __restrict__ out, int R, int C) {
    __shared__ float tile[32][33];
    int c0 = blockIdx.x * 32, r0 = blockIdx.y * 32;
    int tx = threadIdx.x, ty = threadIdx.y;  // 32 x 8
#pragma unroll
    for (int i = 0; i < 4; i++)
        tile[ty + i * 8][tx] = in[(size_t)(r0 + ty + i * 8) * C + c0 + tx];
    __syncthreads();
#pragma unroll
    for (int i = 0; i < 4; i++)
        out[(size_t)(c0 + ty + i * 8) * R + r0 + tx] = f2bf(tile[tx][ty + i * 8]);
}

// W_h [1024][4096] fp32 -> fragment-ordered bf16 pack (K=1024: 32 ksteps)
__global__ void k_pack_wh(const float* __restrict__ Wh, unsigned short* __restrict__ out) {
    int gid = blockIdx.x * 256 + threadIdx.x;  // 524288 = 256 nfrag * 32 ks * 64 lane
    int lane = gid & 63, ks = (gid >> 6) & 31, nfrag = gid >> 11;
    int col = (nfrag & 3) * 1024 + ((nfrag >> 2) << 4) + (lane & 15);
    int kb = ks * 32 + ((lane >> 4) << 3);
    short8 v;
#pragma unroll
    for (int e = 0; e < 8; e++) v[e] = (short)f2bf(Wh[(size_t)(kb + e) * 4096 + col]);
    *reinterpret_cast<short8*>(out + (size_t)gid * 8) = v;
}

__global__ void k_bias(const float* __restrict__ bi, const float* __restrict__ bh, float* __restrict__ bs) {
    int i = blockIdx.x * 256 + threadIdx.x;
    if (i < 4096) bs[i] = bi[i] + bh[i];
}

// ---------------- GEMM1 (chunked): xgc[b*c + s][n] = sum_k text[b*512+s0+s][k] * WinT[n][k]
__global__ __launch_bounds__(256) void k_gemm1(
    const float* __restrict__ A,
    const unsigned short* __restrict__ BT,
    unsigned short* __restrict__ C,
    int s0, int log2c)
{
    __shared__ unsigned short Asl[128 * 40];
    __shared__ unsigned short Bsl[128 * 40];
    const int K = 768, N = 4096;
    int t = threadIdx.x, lane = t & 63, w = t >> 6;
    int m0 = blockIdx.y * 128, n0 = blockIdx.x * 128;
    int wm = (w >> 1) * 64, wn = (w & 1) * 64;
    int cmask = (1 << log2c) - 1;
    float4_t acc[4][4] = {};

    for (int k0 = 0; k0 < K; k0 += 32) {
        __syncthreads();
#pragma unroll
        for (int p = 0; p < 2; p++) {
            int flat = p * 256 + t;
            int row = flat >> 2, kq = flat & 3;
            int row_l = m0 + row;
            int b = row_l >> log2c, s = row_l & cmask;
            const float* ap = A + (size_t)(b * 512 + s0 + s) * K + k0 + kq * 8;
            float4 v0 = *reinterpret_cast<const float4*>(ap);
            float4 v1 = *reinterpret_cast<const float4*>(ap + 4);
            short4_t o0, o1;
            o0[0]=(short)f2bf(v0.x); o0[1]=(short)f2bf(v0.y); o0[2]=(short)f2bf(v0.z); o0[3]=(short)f2bf(v0.w);
            o1[0]=(short)f2bf(v1.x); o1[1]=(short)f2bf(v1.y); o1[2]=(short)f2bf(v1.z); o1[3]=(short)f2bf(v1.w);
            *reinterpret_cast<short4_t*>(&Asl[row * 40 + kq * 8]) = o0;
            *reinterpret_cast<short4_t*>(&Asl[row * 40 + kq * 8 + 4]) = o1;
            short8 vb = *reinterpret_cast<const short8*>(BT + (size_t)(n0 + row) * K + k0 + kq * 8);
            const short4_t* wp = reinterpret_cast<const short4_t*>(&vb);
            *reinterpret_cast<short4_t*>(&Bsl[row * 40 + kq * 8]) = wp[0];
            *reinterpret_cast<short4_t*>(&Bsl[row * 40 + kq * 8 + 4]) = wp[1];
        }
        __syncthreads();
        short8 af[4], bfr[4];
#pragma unroll
        for (int mi = 0; mi < 4; mi++)
            af[mi] = ld_frag8(&Asl[(wm + mi * 16 + (lane & 15)) * 40 + (lane >> 4) * 8]);
#pragma unroll
        for (int ni = 0; ni < 4; ni++)
            bfr[ni] = ld_frag8(&Bsl[(wn + ni * 16 + (lane & 15)) * 40 + (lane >> 4) * 8]);
#pragma unroll
        for (int mi = 0; mi < 4; mi++)
#pragma unroll
            for (int ni = 0; ni < 4; ni++)
                acc[mi][ni] = __builtin_amdgcn_mfma_f32_16x16x32_bf16(af[mi], bfr[ni], acc[mi][ni], 0, 0, 0);
    }

#pragma unroll
    for (int mi = 0; mi < 4; mi++)
#pragma unroll
        for (int ni = 0; ni < 4; ni++)
#pragma unroll
            for (int r = 0; r < 4; r++) {
                int row = m0 + wm + mi * 16 + (lane >> 4) * 4 + r;
                int col = n0 + wn + ni * 16 + (lane & 15);
                C[(size_t)row * N + col] = f2bf(acc[mi][ni][r]);
            }
}

// ---------------- generic bf16 GEMM: C[M][N] = A[M][K] * BT[N][K] ----------------
__global__ __launch_bounds__(256) void k_gemm_bf16(
    const unsigned short* __restrict__ A,
    const unsigned short* __restrict__ BT,
    unsigned short* __restrict__ C,
    int M, int N, int K)
{
    __shared__ unsigned short Asl[128 * 40];
    __shared__ unsigned short Bsl[128 * 40];
    int t = threadIdx.x, lane = t & 63, w = t >> 6;
    int m0 = blockIdx.y * 128, n0 = blockIdx.x * 128;
    int wm = (w >> 1) * 64, wn = (w & 1) * 64;
    float4_t acc[4][4] = {};

    for (int k0 = 0; k0 < K; k0 += 32) {
        __syncthreads();
#pragma unroll
        for (int p = 0; p < 2; p++) {
            int flat = p * 256 + t;
            int row = flat >> 2, kq = flat & 3;
            short8 va = *reinterpret_cast<const short8*>(A + (size_t)(m0 + row) * K + k0 + kq * 8);
            const short4_t* vp = reinterpret_cast<const short4_t*>(&va);
            *reinterpret_cast<short4_t*>(&Asl[row * 40 + kq * 8]) = vp[0];
            *reinterpret_cast<short4_t*>(&Asl[row * 40 + kq * 8 + 4]) = vp[1];
            short8 vb = *reinterpret_cast<const short8*>(BT + (size_t)(n0 + row) * K + k0 + kq * 8);
            const short4_t* wp = reinterpret_cast<const short4_t*>(&vb);
            *reinterpret_cast<short4_t*>(&Bsl[row * 40 + kq * 8]) = wp[0];
            *reinterpret_cast<short4_t*>(&Bsl[row * 40 + kq * 8 + 4]) = wp[1];
        }
        __syncthreads();
        short8 af[4], bfr[4];
#pragma unroll
        for (int mi = 0; mi < 4; mi++)
            af[mi] = ld_frag8(&Asl[(wm + mi * 16 + (lane & 15)) * 40 + (lane >> 4) * 8]);
#pragma unroll
        for (int ni = 0; ni < 4; ni++)
            bfr[ni] = ld_frag8(&Bsl[(wn + ni * 16 + (lane & 15)) * 40 + (lane >> 4) * 8]);
#pragma unroll
        for (int mi = 0; mi < 4; mi++)
#pragma unroll
            for (int ni = 0; ni < 4; ni++)
                acc[mi][ni] = __builtin_amdgcn_mfma_f32_16x16x32_bf16(af[mi], bfr[ni], acc[mi][ni], 0, 0, 0);
    }

#pragma unroll
    for (int mi = 0; mi < 4; mi++)
#pragma unroll
        for (int ni = 0; ni < 4; ni++)
#pragma unroll
            for (int r = 0; r < 4; r++) {
                int row = m0 + wm + mi * 16 + (lane >> 4) * 4 + r;
                int col = n0 + wn + ni * 16 + (lane & 15);
                C[(size_t)row * N + col] = f2bf(acc[mi][ni][r]);
            }
}

// ---------------- persistent LSTM scan: barrier-free, wave-self-contained ----------------
// grid 64 blocks (one per 16-hidden-col tile) x 4 waves.
// Wave w owns batch rows [16w,16w+16) x 16 cols x ALL 4 gates, K=1024 (128 MFMAs).
// Gate accumulators for a (row,col) cell live in ONE lane's registers -> the
// LSTM cell update is register-local: NO LDS partials, NO block barriers in loop.
// Per-wave flags; cohort w (wave w of all 64 blocks) is a closed producer/
// consumer set -> 2-buffer skew safety as before. hs = plain L2 store BEFORE
// the single wave-level vmcnt(0) drain (poll no longer inherits store acks).
__global__ __launch_bounds__(256, 1) void k_scan(
    const unsigned short* __restrict__ xgc,     // [64*c][4096] bf16 chunk
    const unsigned short* __restrict__ WhPack,  // frag-ordered, 32 ksteps
    const float* __restrict__ bias_sum,         // [4096]
    unsigned short* __restrict__ h_bufs,        // [2][64][1024] bf16
    float* __restrict__ c_glob,                 // [64][1024] f32
    unsigned short* __restrict__ hs,            // [64*512][1024] bf16
    unsigned int* __restrict__ flags,           // [64*4*16] padded per-wave flags
    int ts0, int c, int log2c)
{
    __shared__ unsigned short wlds[4 * 32 * 64 * 8];  // 128KB Wh slice (16 cols x 4 gates)

    int t = threadIdx.x, lane = t & 63, w = t >> 6;
    int ut = blockIdx.x;                     // 64 blocks
    int u = lane & 15, lq = lane >> 4;
    int jc = ut * 16 + u;                    // this lane's output col
    // this lane's output rows: w*16 + lq*4 + r, r=0..3 (MFMA C layout)
    float bsv[4];
#pragma unroll
    for (int g = 0; g < 4; g++) bsv[g] = bias_sum[g * 1024 + jc];
    float c_reg[4];
#pragma unroll
    for (int r = 0; r < 4; r++) c_reg[r] = c_glob[(w * 16 + lq * 4 + r) * 1024 + jc];

    // lane l polls wave-w flag of block l
    const unsigned int* pf = &flags[((lane << 2) + w) << 4];
    unsigned int* myf = &flags[(((ut << 2) + w) << 4)];

    // ---- Wh slice (contiguous 65536 ushorts) -> LDS ----
    const unsigned short* wsrc = WhPack + (size_t)ut * 65536;
#pragma unroll
    for (int i = 0; i < 32; i++) {
        int idx = (i * 256 + t) * 8;
        *reinterpret_cast<short8*>(&wlds[idx]) = *reinterpret_cast<const short8*>(wsrc + idx);
    }
    __syncthreads();

    for (int tl = 0; tl < c; tl++) {
        int ts = ts0 + tl;
        const unsigned short* h_in = h_bufs + (size_t)(ts & 1) * 65536;
        unsigned short* h_out = h_bufs + (size_t)((ts + 1) & 1) * 65536;

        // xg prefetch (L2-cached, independent of h)
        float xv[16];
#pragma unroll
        for (int g = 0; g < 4; g++)
#pragma unroll
            for (int r = 0; r < 4; r++)
                xv[g * 4 + r] = bf2f(xgc[((size_t)(((w * 16 + lq * 4 + r) << log2c) + tl)) * 4096
                                        + g * 1024 + jc]);

        // poll: all 64 lanes, one producer flag each (wave-w cohort)
        unsigned want = (unsigned)ts;
        while (__hip_atomic_load(pf, __ATOMIC_RELAXED, __HIP_MEMORY_SCOPE_AGENT) < want)
            __builtin_amdgcn_s_sleep(1);
        __builtin_amdgcn_sched_barrier(0);

        // h loads: rows w*16+u, full K=1024 (32 x 16B), one drain
        const unsigned short* ab = h_in + ((w * 16 + u) << 10) + (lq << 3);
        float4_t araw[32];
#pragma unroll
        for (int ks = 0; ks < 32; ks++)
            araw[ks] = ld_b128_coh_raw(ab + ks * 32);
        asm volatile("s_waitcnt vmcnt(0)" ::: "memory");
        __builtin_amdgcn_sched_barrier(0);

        // 128 MFMAs: 4 gates x 32 ksteps, all in-wave
        float4_t acc[4] = {};
#pragma unroll
        for (int ks = 0; ks < 32; ks++) {
            short8 a = __builtin_bit_cast(short8, araw[ks]);
#pragma unroll
            for (int g = 0; g < 4; g++) {
                short8 b = *reinterpret_cast<const short8*>(&wlds[((g * 32 + ks) * 64 + lane) * 8]);
                acc[g] = __builtin_amdgcn_mfma_f32_16x16x32_bf16(a, b, acc[g], 0, 0, 0);
            }
        }

        // register-local cell update + stores (h_out via IC; hs via L2)
#pragma unroll
        for (int r = 0; r < 4; r++) {
            float rt = sigm(acc[0][r] + bsv[0] + xv[0 * 4 + r]);
            float ft = sigm(acc[1][r] + bsv[1] + xv[1 * 4 + r]);
            float gt = tanh_fast(acc[2][r] + bsv[2] + xv[2 * 4 + r]);
            float ot = sigm(acc[3][r] + bsv[3] + xv[3 * 4 + r]);
            c_reg[r] = ft * c_reg[r] + rt * gt;
            float hn = ot * tanh_fast(c_reg[r]);
            unsigned short hb = f2bf(hn);
            int brow = w * 16 + lq * 4 + r;
            st_b16_coh(&h_out[(brow << 10) + jc], hb);
            hs[(((size_t)(brow * 512 + ts)) << 10) + jc] = hb;
        }
        // single wave-level drain (h_out IC acks + hs L2 acks), then flag
        asm volatile("s_waitcnt vmcnt(0)" ::: "memory");
        __builtin_amdgcn_sched_barrier(0);
        if (lane == 0)
            __hip_atomic_store(myf, (unsigned)(ts + 1), __ATOMIC_RELAXED, __HIP_MEMORY_SCOPE_AGENT);
    }
#pragma unroll
    for (int r = 0; r < 4; r++)
        c_glob[(w * 16 + lq * 4 + r) * 1024 + jc] = c_reg[r];
}

// ---------------- tail kernels ----------------

__global__ void k_fh(const unsigned short* __restrict__ h, const float* __restrict__ Wlo,
                     const float* __restrict__ blo, float* __restrict__ fh) {
    int gid = blockIdx.x * 256 + threadIdx.x;  // 32768
    int b = gid >> 9, d = gid & 511;
    float acc = blo[d];
    for (int k = 0; k < 1024; k++) acc += bf2f(h[b * 1024 + k]) * Wlo[k * 512 + d];
    fh[gid] = acc;
}

__global__ void k_wsb(const float* __restrict__ fh, const float* __restrict__ Was,
                      const float* __restrict__ bas, float* __restrict__ WSb) {
    int gid = blockIdx.x * 256 + threadIdx.x;  // 16384
    int b = gid >> 8, v = gid & 255;
    float acc = bas[v];
    for (int k = 0; k < 512; k++) acc += fh[b * 512 + k] * Was[k * 256 + v];
    WSb[gid] = acc;
}

__global__ void k_score(const unsigned short* __restrict__ WH, const float* __restrict__ bah,
                        const float* __restrict__ WSb, const float* __restrict__ Wv,
                        const float* __restrict__ bv, float* __restrict__ score) {
    int row = blockIdx.x * 4 + (threadIdx.x >> 6);  // 32768 rows
    int lane = threadIdx.x & 63;
    int b = row >> 9;
    float acc = 0.f;
#pragma unroll
    for (int q = 0; q < 4; q++) {
        int v = q * 64 + lane;
        float val = bf2f(WH[(size_t)row * 256 + v]) + bah[v] + WSb[b * 256 + v];
        acc += tanhf(val) * Wv[v];
    }
#pragma unroll
    for (int o = 32; o; o >>= 1) acc += __shfl_down(acc, o);
    if (lane == 0) score[row] = acc + bv[0];
}

__global__ __launch_bounds__(512) void k_softmax(const float* __restrict__ score, float* __restrict__ attn) {
    __shared__ float red[8];
    __shared__ float red2[8];
    int b = blockIdx.x, t = threadIdx.x;
    float x = score[b * 512 + t];
    float m = x;
#pragma unroll
    for (int o = 32; o; o >>= 1) m = fmaxf(m, __shfl_xor(m, o));
    if ((t & 63) == 0) red[t >> 6] = m;
    __syncthreads();
    if (t == 0) { float mm = red[0]; for (int i = 1; i < 8; i++) mm = fmaxf(mm, red[i]); red[0] = mm; }
    __syncthreads();
    m = red[0];
    float e = __expf(x - m);
    float s = e;
#pragma unroll
    for (int o = 32; o; o >>= 1) s += __shfl_xor(s, o);
    if ((t & 63) == 0) red2[t >> 6] = s;
    __syncthreads();
    if (t == 0) { float ss = 0.f; for (int i = 0; i < 8; i++) ss += red2[i]; red2[0] = ss; }
    __syncthreads();
    attn[b * 512 + t] = e / red2[0];
}

__global__ void k_attnout(const unsigned short* __restrict__ hs, const float* __restrict__ attn,
                          float* __restrict__ ao) {
    __shared__ float a_s[512];
    int b = blockIdx.x >> 2;
    int hcol = (blockIdx.x & 3) * 256 + threadIdx.x;
    a_s[threadIdx.x] = attn[b * 512 + threadIdx.x];
    a_s[256 + threadIdx.x] = attn[b * 512 + 256 + threadIdx.x];
    __syncthreads();
    float acc = 0.f;
    for (int s = 0; s < 512; s++)
        acc += bf2f(hs[((size_t)(b * 512 + s)) * 1024 + hcol]) * a_s[s];
    ao[b * 1024 + hcol] = acc;
}

__global__ void k_out(const float* __restrict__ fh, const float* __restrict__ ao,
                      const float* __restrict__ Wout, const float* __restrict__ bout,
                      float* __restrict__ out) {
    int t = threadIdx.x;
    if (t >= 128) return;
    int b = t >> 1, o = t & 1;
    float acc = bout[o];
    for (int k = 0; k < 512; k++) acc += fh[b * 512 + k] * Wout[k * 2 + o];
    for (int k = 0; k < 1024; k++) acc += ao[b * 1024 + k] * Wout[(512 + k) * 2 + o];
    out[b * 2 + o] = sigm(acc);
}

// ---------------- launch ----------------

extern "C" void kernel_launch(void* const* d_in, const int* in_sizes, int n_in,
                              void* d_out, int out_size, void* d_ws, size_t ws_size,
                              hipStream_t stream) {
    const float* text  = (const float*)d_in[0];
    const float* W_in  = (const float*)d_in[1];
    const float* b_in  = (const float*)d_in[2];
    const float* W_h   = (const float*)d_in[3];
    const float* b_h   = (const float*)d_in[4];
    const float* W_ah  = (const float*)d_in[5];
    const float* b_ah  = (const float*)d_in[6];
    const float* W_as  = (const float*)d_in[7];
    const float* b_as  = (const float*)d_in[8];
    const float* W_v   = (const float*)d_in[9];
    const float* b_v   = (const float*)d_in[10];
    const float* W_lo  = (const float*)d_in[11];
    const float* b_lo  = (const float*)d_in[12];
    const float* W_out = (const float*)d_in[13];
    const float* b_out = (const float*)d_in[14];
    float* out = (float*)d_out;

    char* ws = (char*)d_ws;
    size_t off = 0;
    auto alloc = [&](size_t bytes) {
        void* p = ws + off;
        off = (off + bytes + 255) & ~(size_t)255;
        return p;
    };
    // fixed buffers
    unsigned short* WinT    = (unsigned short*)alloc((size_t)4096 * 768 * 2);
    unsigned short* WhPack  = (unsigned short*)alloc((size_t)4096 * 1024 * 2);
    unsigned short* WahT    = (unsigned short*)alloc((size_t)256 * 1024 * 2);
    float*          biassum = (float*)alloc(4096 * 4);
    unsigned short* hsbuf   = (unsigned short*)alloc((size_t)32768 * 1024 * 2);
    unsigned short* h_bf    = (unsigned short*)alloc((size_t)2 * 65536 * 2);
    float*          c_glob  = (float*)alloc(65536 * 4);
    float*          fh      = (float*)alloc(32768 * 4);
    float*          WSb     = (float*)alloc(16384 * 4);
    float*          score   = (float*)alloc(32768 * 4);
    float*          attn    = (float*)alloc(32768 * 4);
    float*          ao      = (float*)alloc(65536 * 4);
    unsigned int*   flags   = (unsigned int*)alloc(64 * 4 * 16 * 4);  // per-wave padded flags

    // variable region: xg chunk while scanning; WHb afterwards (aliased)
    size_t remain = (ws_size > off + 4096) ? (ws_size - off - 4096) : 0;
    int c = 2;
    for (int cc = 512; cc >= 2; cc >>= 1) {
        size_t need = (size_t)64 * cc * 4096 * 2;
        size_t whb  = (size_t)32768 * 256 * 2;
        if ((need > whb ? need : whb) <= remain) { c = cc; break; }
    }
    int log2c = __builtin_ctz(c);
    unsigned short* xgc = (unsigned short*)alloc(1);
    unsigned short* WHb = xgc;

    // prep
    dim3 tb(32, 8);
    k_transpose_bf16<<<dim3(4096 / 32, 768 / 32), tb, 0, stream>>>(W_in, WinT, 768, 4096);
    k_transpose_bf16<<<dim3(256 / 32, 1024 / 32), tb, 0, stream>>>(W_ah, WahT, 1024, 256);
    k_pack_wh<<<2048, 256, 0, stream>>>(W_h, WhPack);
    k_bias<<<16, 256, 0, stream>>>(b_in, b_h, biassum);
    hipMemsetAsync(h_bf, 0, (size_t)2 * 65536 * 2, stream);
    hipMemsetAsync(c_glob, 0, 65536 * 4, stream);
    hipMemsetAsync(flags, 0, 64 * 4 * 16 * 4, stream);

    // chunked scan: GEMM1 for c timesteps, then barrier-free persistent scan
    int nch = 512 / c;
    for (int ch = 0; ch < nch; ch++) {
        k_gemm1<<<dim3(32, c / 2), 256, 0, stream>>>(text, WinT, xgc, ch * c, log2c);
        k_scan<<<64, 256, 0, stream>>>(xgc, WhPack, biassum, h_bf, c_glob,
                                       hsbuf, flags, ch * c, c, log2c);
    }

    // tail (h after step 511 lives in buffer (512 & 1) == 0)
    k_fh<<<128, 256, 0, stream>>>(h_bf, W_lo, b_lo, fh);
    k_wsb<<<64, 256, 0, stream>>>(fh, W_as, b_as, WSb);
    k_gemm_bf16<<<dim3(2, 256), 256, 0, stream>>>(hsbuf, WahT, WHb, 32768, 256, 1024);
    k_score<<<8192, 256, 0, stream>>>(WHb, b_ah, WSb, W_v, b_v, score);
    k_softmax<<<64, 512, 0, stream>>>(score, attn);
    k_attnout<<<256, 256, 0, stream>>>(hsbuf, attn, ao);
    k_out<<<1, 128, 0, stream>>>(fh, ao, W_out, b_out, out);
}

// Round 11
// 4021.995 us; speedup vs baseline: 1.2238x; 1.2238x over previous
//
#include <hip/hip_runtime.h>
#include <hip/hip_bf16.h>
#include <cmath>

typedef __attribute__((ext_vector_type(8))) short short8;
typedef __attribute__((ext_vector_type(4))) short short4_t;
typedef __attribute__((ext_vector_type(4))) float float4_t;

__device__ __forceinline__ float bf2f(unsigned short u) {
    union { unsigned int i; float f; } v; v.i = ((unsigned int)u) << 16; return v.f;
}
__device__ __forceinline__ unsigned short f2bf(float f) {
    union { float f; unsigned int i; } v; v.f = f;
    unsigned int r = v.i + 0x7FFF + ((v.i >> 16) & 1);  // round-to-nearest-even
    return (unsigned short)(r >> 16);
}
__device__ __forceinline__ float sigm(float x) { return 1.f / (1.f + __expf(-x)); }
__device__ __forceinline__ float tanh_fast(float x) {
    float e = __expf(2.f * x);
    return 1.f - 2.f / (e + 1.f);
}

// coherence-point (IC) ops: bypass non-coherent L1/L2 on both sides
__device__ __forceinline__ void st_b16_coh(unsigned short* p, unsigned short v) {
    asm volatile("global_store_short %0, %1, off sc0 sc1" :: "v"(p), "v"((unsigned int)v) : "memory");
}
__device__ __forceinline__ float4_t ld_b128_coh_raw(const unsigned short* p) {
    float4_t v;
    asm volatile("global_load_dwordx4 %0, %1, off sc0 sc1" : "=v"(v) : "v"(p));
    return v;  // NOT READY until s_waitcnt vmcnt(0)
}

__device__ __forceinline__ short8 ld_frag8(const unsigned short* p) {
    short4_t a = *reinterpret_cast<const short4_t*>(p);
    short4_t b = *reinterpret_cast<const short4_t*>(p + 4);
    short8 v;
    v[0]=a[0]; v[1]=a[1]; v[2]=a[2]; v[3]=a[3];
    v[4]=b[0]; v[5]=b[1]; v[6]=b[2]; v[7]=b[3];
    return v;
}

// ---------------- prep kernels ----------------

// in: fp32 [R][C]  ->  out: bf16 [C][R]
__global__ void k_transpose_bf16(const float* __restrict__ in, unsigned short* __restrict__ out, int R, int C) {
    __shared__ float tile[32][33];
    int c0 = blockIdx.x * 32, r0 = blockIdx.y * 32;
    int tx = threadIdx.x, ty = threadIdx.y;  // 32 x 8
#pragma unroll
    for (int i = 0; i < 4; i++)
        tile[ty + i * 8][tx] = in[(size_t)(r0 + ty + i * 8) * C + c0 + tx];
    __syncthreads();
#pragma unroll
    for (int i = 0; i < 4; i++)
        out[(size_t)(c0 + ty + i * 8) * R + r0 + tx] = f2bf(tile[tx][ty + i * 8]);
}

// W_h [1024][4096] fp32 -> fragment-ordered bf16 pack (K=1024: 32 ksteps)
__global__ void k_pack_wh(const float* __restrict__ Wh, unsigned short* __restrict__ out) {
    int gid = blockIdx.x * 256 + threadIdx.x;  // 524288 = 256 nfrag * 32 ks * 64 lane
    int lane = gid & 63, ks = (gid >> 6) & 31, nfrag = gid >> 11;
    int col = (nfrag & 3) * 1024 + ((nfrag >> 2) << 4) + (lane & 15);
    int kb = ks * 32 + ((lane >> 4) << 3);
    short8 v;
#pragma unroll
    for (int e = 0; e < 8; e++) v[e] = (short)f2bf(Wh[(size_t)(kb + e) * 4096 + col]);
    *reinterpret_cast<short8*>(out + (size_t)gid * 8) = v;
}

// W_in [768][4096] fp32 -> fragment-ordered bf16 pack (K=768: 24 ksteps)
__global__ void k_pack_win(const float* __restrict__ Win, unsigned short* __restrict__ out) {
    int gid = blockIdx.x * 256 + threadIdx.x;  // 393216 = 256 nfrag * 24 ks * 64 lane
    int lane = gid & 63;
    int comp = gid >> 6;           // nfrag*24 + ks
    int ks = comp % 24, nfrag = comp / 24;
    int col = (nfrag & 3) * 1024 + ((nfrag >> 2) << 4) + (lane & 15);
    int kb = ks * 32 + ((lane >> 4) << 3);
    short8 v;
#pragma unroll
    for (int e = 0; e < 8; e++) v[e] = (short)f2bf(Win[(size_t)(kb + e) * 4096 + col]);
    *reinterpret_cast<short8*>(out + (size_t)gid * 8) = v;
}

__global__ void k_bias(const float* __restrict__ bi, const float* __restrict__ bh, float* __restrict__ bs) {
    int i = blockIdx.x * 256 + threadIdx.x;
    if (i < 4096) bs[i] = bi[i] + bh[i];
}

// ---------------- generic bf16 GEMM: C[M][N] = A[M][K] * BT[N][K] ----------------
__global__ __launch_bounds__(256) void k_gemm_bf16(
    const unsigned short* __restrict__ A,
    const unsigned short* __restrict__ BT,
    unsigned short* __restrict__ C,
    int M, int N, int K)
{
    __shared__ unsigned short Asl[128 * 40];
    __shared__ unsigned short Bsl[128 * 40];
    int t = threadIdx.x, lane = t & 63, w = t >> 6;
    int m0 = blockIdx.y * 128, n0 = blockIdx.x * 128;
    int wm = (w >> 1) * 64, wn = (w & 1) * 64;
    float4_t acc[4][4] = {};

    for (int k0 = 0; k0 < K; k0 += 32) {
        __syncthreads();
#pragma unroll
        for (int p = 0; p < 2; p++) {
            int flat = p * 256 + t;
            int row = flat >> 2, kq = flat & 3;
            short8 va = *reinterpret_cast<const short8*>(A + (size_t)(m0 + row) * K + k0 + kq * 8);
            const short4_t* vp = reinterpret_cast<const short4_t*>(&va);
            *reinterpret_cast<short4_t*>(&Asl[row * 40 + kq * 8]) = vp[0];
            *reinterpret_cast<short4_t*>(&Asl[row * 40 + kq * 8 + 4]) = vp[1];
            short8 vb = *reinterpret_cast<const short8*>(BT + (size_t)(n0 + row) * K + k0 + kq * 8);
            const short4_t* wp = reinterpret_cast<const short4_t*>(&vb);
            *reinterpret_cast<short4_t*>(&Bsl[row * 40 + kq * 8]) = wp[0];
            *reinterpret_cast<short4_t*>(&Bsl[row * 40 + kq * 8 + 4]) = wp[1];
        }
        __syncthreads();
        short8 af[4], bfr[4];
#pragma unroll
        for (int mi = 0; mi < 4; mi++)
            af[mi] = ld_frag8(&Asl[(wm + mi * 16 + (lane & 15)) * 40 + (lane >> 4) * 8]);
#pragma unroll
        for (int ni = 0; ni < 4; ni++)
            bfr[ni] = ld_frag8(&Bsl[(wn + ni * 16 + (lane & 15)) * 40 + (lane >> 4) * 8]);
#pragma unroll
        for (int mi = 0; mi < 4; mi++)
#pragma unroll
            for (int ni = 0; ni < 4; ni++)
                acc[mi][ni] = __builtin_amdgcn_mfma_f32_16x16x32_bf16(af[mi], bfr[ni], acc[mi][ni], 0, 0, 0);
    }

#pragma unroll
    for (int mi = 0; mi < 4; mi++)
#pragma unroll
        for (int ni = 0; ni < 4; ni++)
#pragma unroll
            for (int r = 0; r < 4; r++) {
                int row = m0 + wm + mi * 16 + (lane >> 4) * 4 + r;
                int col = n0 + wn + ni * 16 + (lane & 15);
                C[(size_t)row * N + col] = f2bf(acc[mi][ni][r]);
            }
}

// ---------------- fused persistent scan: wave-specialized producers ----------------
// grid 256 = 64 col-tiles x 4 batch-quarters; block 512 = 8 waves.
// Waves 0-3 (scan): round-7 h-recurrence. Wave w: K-quarter [w*256,(w+1)*256),
//   4 gates, part[] combine, IC h-exchange via sc0/sc1 + padded flags +
//   wave-local poll. xg read from LDS ring (not global).
// Waves 4-7 (producers): wave 4+g holds gate g's Win fragments in regs
//   (24 x short8 = 96 VGPR, static idx) and computes the block's 16x64 xg
//   tile for step ts+2 into ring[(ts+2)&3] during the scan waves' stall
//   phase. Sync = the two existing block barriers (>=2-barrier separation
//   between ring write and read; deterministic, no new cross-block protocol).
__global__ __launch_bounds__(512, 1) void k_scan(
    const float* __restrict__ text,             // [64*512][768] f32
    const unsigned short* __restrict__ WhPack,  // frag-ordered, 32 ksteps
    const unsigned short* __restrict__ WinPack, // frag-ordered, 24 ksteps
    const float* __restrict__ bias_sum,         // [4096]
    unsigned short* __restrict__ h_bufs,        // [2][64][1024] bf16
    unsigned short* __restrict__ hs,            // [64*512][1024] bf16
    unsigned int* __restrict__ flags)           // [256*16] padded arrival flags
{
    __shared__ unsigned short wlds[4 * 32 * 64 * 8];  // 128KB Wh slice
    __shared__ float part[4 * 4 * 16 * 17];           // 17KB partials
    __shared__ unsigned short ring[4][16][64];        // 8KB xg ring (4 steps deep)

    int t = threadIdx.x, lane = t & 63, w = t >> 6;   // w in 0..7
    int bb = blockIdx.x;
    int ut = bb >> 2, mq = bb & 3;
    int u = lane & 15, lq = lane >> 4;
    int ml = (t & 255) >> 4, u2 = t & 15;
    int brow_c = mq * 16 + ml;               // combine-owned batch row (t<256)
    int jcol = ut * 16 + u2;                 // combine-owned hidden col
    int brow_a = mq * 16 + u;                // A-fragment batch row
    float c_reg = 0.f;
    float bsv[4];
#pragma unroll
    for (int g = 0; g < 4; g++) bsv[g] = bias_sum[g * 1024 + jcol];

    // scan waves: producer flags to poll (wave w needs col-tiles w*16+i, i=lane<16)
    const unsigned int* myflag = &flags[((((w << 4) + lane) << 2) + mq) << 4];

    int gw = w & 3;  // producer wave's gate (w>=4)

    // ---- producer waves: Win fragments (gate gw, 24 ksteps) -> registers ----
    short8 wfx[24];
    if (w >= 4) {
#pragma unroll
        for (int ks = 0; ks < 24; ks++)
            wfx[ks] = *reinterpret_cast<const short8*>(
                WinPack + (((size_t)((ut * 4 + gw) * 24 + ks)) << 9) + lane * 8);
    }

    // ---- Wh slice (contiguous 65536 ushorts) -> LDS (512 threads) ----
    const unsigned short* wsrc = WhPack + (size_t)ut * 65536;
#pragma unroll
    for (int i = 0; i < 16; i++) {
        int idx = (i * 512 + t) * 8;
        *reinterpret_cast<short8*>(&wlds[idx]) = *reinterpret_cast<const short8*>(wsrc + idx);
    }

    // ---- priming: producers fill ring slots 0,1 (steps 0,1) ----
    if (w >= 4) {
#pragma unroll
        for (int pt = 0; pt < 2; pt++) {
            const float* tp = text + ((size_t)(brow_a * 512 + pt)) * 768 + lq * 8;
            float4_t xacc = {0.f, 0.f, 0.f, 0.f};
#pragma unroll
            for (int ks = 0; ks < 24; ks++) {
                float4 a0 = *reinterpret_cast<const float4*>(tp + ks * 32);
                float4 a1 = *reinterpret_cast<const float4*>(tp + ks * 32 + 4);
                short8 a;
                a[0]=(short)f2bf(a0.x); a[1]=(short)f2bf(a0.y); a[2]=(short)f2bf(a0.z); a[3]=(short)f2bf(a0.w);
                a[4]=(short)f2bf(a1.x); a[5]=(short)f2bf(a1.y); a[6]=(short)f2bf(a1.z); a[7]=(short)f2bf(a1.w);
                xacc = __builtin_amdgcn_mfma_f32_16x16x32_bf16(a, wfx[ks], xacc, 0, 0, 0);
            }
#pragma unroll
            for (int r = 0; r < 4; r++)
                ring[pt][lq * 4 + r][gw * 16 + u] = f2bf(xacc[r]);
        }
    }
    __syncthreads();

    for (int ts = 0; ts < 512; ts++) {
        const unsigned short* h_in = h_bufs + (size_t)(ts & 1) * 65536;
        unsigned short* h_out = h_bufs + (size_t)((ts + 1) & 1) * 65536;

        if (w < 4) {
            // h loads via coherence point, one drain
            const unsigned short* abase = h_in + (brow_a << 10) + (lq << 3);
            float4_t araw[8];
#pragma unroll
            for (int kk = 0; kk < 8; kk++)
                araw[kk] = ld_b128_coh_raw(abase + (w * 8 + kk) * 32);
            asm volatile("s_waitcnt vmcnt(0)" ::: "memory");
            __builtin_amdgcn_sched_barrier(0);

            float4_t acc[4] = {};
#pragma unroll
            for (int kk = 0; kk < 8; kk++) {
                short8 a = __builtin_bit_cast(short8, araw[kk]);
#pragma unroll
                for (int g = 0; g < 4; g++) {
                    short8 b = *reinterpret_cast<const short8*>(&wlds[((g * 32 + w * 8 + kk) * 64 + lane) * 8]);
                    acc[g] = __builtin_amdgcn_mfma_f32_16x16x32_bf16(a, b, acc[g], 0, 0, 0);
                }
            }
#pragma unroll
            for (int g = 0; g < 4; g++)
#pragma unroll
                for (int r = 0; r < 4; r++)
                    part[((w * 4 + g) * 16 + lq * 4 + r) * 17 + u] = acc[g][r];
        } else {
            // producer: xg for step ts+2 into ring[(ts+2)&3]
            int tt = ts + 2;
            if (tt < 512) {
                const float* tp = text + ((size_t)(brow_a * 512 + tt)) * 768 + lq * 8;
                float4_t xacc = {0.f, 0.f, 0.f, 0.f};
#pragma unroll
                for (int ks = 0; ks < 24; ks++) {
                    float4 a0 = *reinterpret_cast<const float4*>(tp + ks * 32);
                    float4 a1 = *reinterpret_cast<const float4*>(tp + ks * 32 + 4);
                    short8 a;
                    a[0]=(short)f2bf(a0.x); a[1]=(short)f2bf(a0.y); a[2]=(short)f2bf(a0.z); a[3]=(short)f2bf(a0.w);
                    a[4]=(short)f2bf(a1.x); a[5]=(short)f2bf(a1.y); a[6]=(short)f2bf(a1.z); a[7]=(short)f2bf(a1.w);
                    xacc = __builtin_amdgcn_mfma_f32_16x16x32_bf16(a, wfx[ks], xacc, 0, 0, 0);
                }
                int slot = tt & 3;
#pragma unroll
                for (int r = 0; r < 4; r++)
                    ring[slot][lq * 4 + r][gw * 16 + u] = f2bf(xacc[r]);
            }
        }
        __syncthreads();  // bar1: part[] + (prior) ring writes visible

        if (w < 4) {
            // combine: thread t (<256) owns (brow_c, jcol)
            float gv[4];
#pragma unroll
            for (int g = 0; g < 4; g++) {
                float s = 0.f;
#pragma unroll
                for (int wv = 0; wv < 4; wv++) s += part[((wv * 4 + g) * 16 + ml) * 17 + u2];
                gv[g] = s + bsv[g] + bf2f(ring[ts & 3][ml][g * 16 + u2]);
            }
            float rt = sigm(gv[0]), ft = sigm(gv[1]), gt = tanh_fast(gv[2]), ot = sigm(gv[3]);
            c_reg = ft * c_reg + rt * gt;
            float hn = ot * tanh_fast(c_reg);
            unsigned short hb = f2bf(hn);
            st_b16_coh(&h_out[(brow_c << 10) + jcol], hb);
            hs[(((size_t)(brow_c * 512 + ts)) << 10) + jcol] = hb;  // L2 ack overlaps IC ack at bar2
        }

        if (ts != 511) {
            __syncthreads();  // bar2: release drain (vmcnt(0) covers h IC + hs stores)
            if (t == 0)
                __hip_atomic_store(&flags[bb * 16], (unsigned)(ts + 1),
                                   __ATOMIC_RELAXED, __HIP_MEMORY_SCOPE_AGENT);
            if (w < 4 && lane < 16) {
                unsigned want = (unsigned)(ts + 1);
                while (__hip_atomic_load(myflag, __ATOMIC_RELAXED, __HIP_MEMORY_SCOPE_AGENT) < want)
                    __builtin_amdgcn_s_sleep(1);
            }
            __builtin_amdgcn_sched_barrier(0);
        } else {
            __syncthreads();
        }
    }
}

// ---------------- tail kernels ----------------

__global__ void k_fh(const unsigned short* __restrict__ h, const float* __restrict__ Wlo,
                     const float* __restrict__ blo, float* __restrict__ fh) {
    int gid = blockIdx.x * 256 + threadIdx.x;  // 32768
    int b = gid >> 9, d = gid & 511;
    float acc = blo[d];
    for (int k = 0; k < 1024; k++) acc += bf2f(h[b * 1024 + k]) * Wlo[k * 512 + d];
    fh[gid] = acc;
}

__global__ void k_wsb(const float* __restrict__ fh, const float* __restrict__ Was,
                      const float* __restrict__ bas, float* __restrict__ WSb) {
    int gid = blockIdx.x * 256 + threadIdx.x;  // 16384
    int b = gid >> 8, v = gid & 255;
    float acc = bas[v];
    for (int k = 0; k < 512; k++) acc += fh[b * 512 + k] * Was[k * 256 + v];
    WSb[gid] = acc;
}

__global__ void k_score(const unsigned short* __restrict__ WH, const float* __restrict__ bah,
                        const float* __restrict__ WSb, const float* __restrict__ Wv,
                        const float* __restrict__ bv, float* __restrict__ score) {
    int row = blockIdx.x * 4 + (threadIdx.x >> 6);  // 32768 rows
    int lane = threadIdx.x & 63;
    int b = row >> 9;
    float acc = 0.f;
#pragma unroll
    for (int q = 0; q < 4; q++) {
        int v = q * 64 + lane;
        float val = bf2f(WH[(size_t)row * 256 + v]) + bah[v] + WSb[b * 256 + v];
        acc += tanhf(val) * Wv[v];
    }
#pragma unroll
    for (int o = 32; o; o >>= 1) acc += __shfl_down(acc, o);
    if (lane == 0) score[row] = acc + bv[0];
}

__global__ __launch_bounds__(512) void k_softmax(const float* __restrict__ score, float* __restrict__ attn) {
    __shared__ float red[8];
    __shared__ float red2[8];
    int b = blockIdx.x, t = threadIdx.x;
    float x = score[b * 512 + t];
    float m = x;
#pragma unroll
    for (int o = 32; o; o >>= 1) m = fmaxf(m, __shfl_xor(m, o));
    if ((t & 63) == 0) red[t >> 6] = m;
    __syncthreads();
    if (t == 0) { float mm = red[0]; for (int i = 1; i < 8; i++) mm = fmaxf(mm, red[i]); red[0] = mm; }
    __syncthreads();
    m = red[0];
    float e = __expf(x - m);
    float s = e;
#pragma unroll
    for (int o = 32; o; o >>= 1) s += __shfl_xor(s, o);
    if ((t & 63) == 0) red2[t >> 6] = s;
    __syncthreads();
    if (t == 0) { float ss = 0.f; for (int i = 0; i < 8; i++) ss += red2[i]; red2[0] = ss; }
    __syncthreads();
    attn[b * 512 + t] = e / red2[0];
}

__global__ void k_attnout(const unsigned short* __restrict__ hs, const float* __restrict__ attn,
                          float* __restrict__ ao) {
    __shared__ float a_s[512];
    int b = blockIdx.x >> 2;
    int hcol = (blockIdx.x & 3) * 256 + threadIdx.x;
    a_s[threadIdx.x] = attn[b * 512 + threadIdx.x];
    a_s[256 + threadIdx.x] = attn[b * 512 + 256 + threadIdx.x];
    __syncthreads();
    float acc = 0.f;
    for (int s = 0; s < 512; s++)
        acc += bf2f(hs[((size_t)(b * 512 + s)) * 1024 + hcol]) * a_s[s];
    ao[b * 1024 + hcol] = acc;
}

__global__ void k_out(const float* __restrict__ fh, const float* __restrict__ ao,
                      const float* __restrict__ Wout, const float* __restrict__ bout,
                      float* __restrict__ out) {
    int t = threadIdx.x;
    if (t >= 128) return;
    int b = t >> 1, o = t & 1;
    float acc = bout[o];
    for (int k = 0; k < 512; k++) acc += fh[b * 512 + k] * Wout[k * 2 + o];
    for (int k = 0; k < 1024; k++) acc += ao[b * 1024 + k] * Wout[(512 + k) * 2 + o];
    out[b * 2 + o] = sigm(acc);
}

// ---------------- launch ----------------

extern "C" void kernel_launch(void* const* d_in, const int* in_sizes, int n_in,
                              void* d_out, int out_size, void* d_ws, size_t ws_size,
                              hipStream_t stream) {
    const float* text  = (const float*)d_in[0];
    const float* W_in  = (const float*)d_in[1];
    const float* b_in  = (const float*)d_in[2];
    const float* W_h   = (const float*)d_in[3];
    const float* b_h   = (const float*)d_in[4];
    const float* W_ah  = (const float*)d_in[5];
    const float* b_ah  = (const float*)d_in[6];
    const float* W_as  = (const float*)d_in[7];
    const float* b_as  = (const float*)d_in[8];
    const float* W_v   = (const float*)d_in[9];
    const float* b_v   = (const float*)d_in[10];
    const float* W_lo  = (const float*)d_in[11];
    const float* b_lo  = (const float*)d_in[12];
    const float* W_out = (const float*)d_in[13];
    const float* b_out = (const float*)d_in[14];
    float* out = (float*)d_out;

    char* ws = (char*)d_ws;
    size_t off = 0;
    auto alloc = [&](size_t bytes) {
        void* p = ws + off;
        off = (off + bytes + 255) & ~(size_t)255;
        return p;
    };
    unsigned short* WhPack  = (unsigned short*)alloc((size_t)4096 * 1024 * 2);
    unsigned short* WinPack = (unsigned short*)alloc((size_t)4096 * 768 * 2);
    unsigned short* WahT    = (unsigned short*)alloc((size_t)256 * 1024 * 2);
    float*          biassum = (float*)alloc(4096 * 4);
    unsigned short* hsbuf   = (unsigned short*)alloc((size_t)32768 * 1024 * 2);
    unsigned short* h_bf    = (unsigned short*)alloc((size_t)2 * 65536 * 2);
    unsigned short* WHb     = (unsigned short*)alloc((size_t)32768 * 256 * 2);
    float*          fh      = (float*)alloc(32768 * 4);
    float*          WSb     = (float*)alloc(16384 * 4);
    float*          score   = (float*)alloc(32768 * 4);
    float*          attn    = (float*)alloc(32768 * 4);
    float*          ao      = (float*)alloc(65536 * 4);
    unsigned int*   flags   = (unsigned int*)alloc(256 * 16 * 4);

    // prep
    dim3 tb(32, 8);
    k_transpose_bf16<<<dim3(256 / 32, 1024 / 32), tb, 0, stream>>>(W_ah, WahT, 1024, 256);
    k_pack_wh<<<2048, 256, 0, stream>>>(W_h, WhPack);
    k_pack_win<<<1536, 256, 0, stream>>>(W_in, WinPack);
    k_bias<<<16, 256, 0, stream>>>(b_in, b_h, biassum);
    hipMemsetAsync(h_bf, 0, (size_t)2 * 65536 * 2, stream);
    hipMemsetAsync(flags, 0, 256 * 16 * 4, stream);

    // fused wave-specialized scan (single launch; input GEMM runs in producer waves)
    k_scan<<<256, 512, 0, stream>>>(text, WhPack, WinPack, biassum, h_bf, hsbuf, flags);

    // tail (h after step 511 lives in buffer (512 & 1) == 0)
    k_fh<<<128, 256, 0, stream>>>(h_bf, W_lo, b_lo, fh);
    k_wsb<<<64, 256, 0, stream>>>(fh, W_as, b_as, WSb);
    k_gemm_bf16<<<dim3(2, 256), 256, 0, stream>>>(hsbuf, WahT, WHb, 32768, 256, 1024);
    k_score<<<8192, 256, 0, stream>>>(WHb, b_ah, WSb, W_v, b_v, score);
    k_softmax<<<64, 512, 0, stream>>>(score, attn);
    k_attnout<<<256, 256, 0, stream>>>(hsbuf, attn, ao);
    k_out<<<1, 128, 0, stream>>>(fh, ao, W_out, b_out, out);
}

// Round 12
// 1987.832 us; speedup vs baseline: 2.4761x; 2.0233x over previous
//
#include <hip/hip_runtime.h>
#include <hip/hip_bf16.h>
#include <cmath>

typedef __attribute__((ext_vector_type(8))) short short8;
typedef __attribute__((ext_vector_type(4))) short short4_t;
typedef __attribute__((ext_vector_type(4))) float float4_t;

__device__ __forceinline__ float bf2f(unsigned short u) {
    union { unsigned int i; float f; } v; v.i = ((unsigned int)u) << 16; return v.f;
}
__device__ __forceinline__ unsigned short f2bf(float f) {
    union { float f; unsigned int i; } v; v.f = f;
    unsigned int r = v.i + 0x7FFF + ((v.i >> 16) & 1);  // round-to-nearest-even
    return (unsigned short)(r >> 16);
}
__device__ __forceinline__ float sigm(float x) { return 1.f / (1.f + __expf(-x)); }
__device__ __forceinline__ float tanh_fast(float x) {
    float e = __expf(2.f * x);
    return 1.f - 2.f / (e + 1.f);
}

// coherence-point (IC) ops: bypass non-coherent L1/L2 on both sides
__device__ __forceinline__ void st_b16_coh(unsigned short* p, unsigned short v) {
    asm volatile("global_store_short %0, %1, off sc0 sc1" :: "v"(p), "v"((unsigned int)v) : "memory");
}
__device__ __forceinline__ float4_t ld_b128_coh_raw(const unsigned short* p) {
    float4_t v;
    asm volatile("global_load_dwordx4 %0, %1, off sc0 sc1" : "=v"(v) : "v"(p));
    return v;  // NOT READY until s_waitcnt vmcnt(0)
}

__device__ __forceinline__ short8 ld_frag8(const unsigned short* p) {
    short4_t a = *reinterpret_cast<const short4_t*>(p);
    short4_t b = *reinterpret_cast<const short4_t*>(p + 4);
    short8 v;
    v[0]=a[0]; v[1]=a[1]; v[2]=a[2]; v[3]=a[3];
    v[4]=b[0]; v[5]=b[1]; v[6]=b[2]; v[7]=b[3];
    return v;
}

// ---------------- prep kernels ----------------

__global__ void k_f32_to_bf16(const float* __restrict__ in, unsigned short* __restrict__ out, int n) {
    int i = (blockIdx.x * blockDim.x + threadIdx.x) * 4;
    if (i + 3 < n) {
        float4 v = *reinterpret_cast<const float4*>(in + i);
        short4_t o;
        o[0] = (short)f2bf(v.x); o[1] = (short)f2bf(v.y);
        o[2] = (short)f2bf(v.z); o[3] = (short)f2bf(v.w);
        *reinterpret_cast<short4_t*>(out + i) = o;
    } else {
        for (; i < n; i++) out[i] = f2bf(in[i]);
    }
}

// in: fp32 [R][C]  ->  out: bf16 [C][R]
__global__ void k_transpose_bf16(const float* __restrict__ in, unsigned short* __restrict__ out, int R, int C) {
    __shared__ float tile[32][33];
    int c0 = blockIdx.x * 32, r0 = blockIdx.y * 32;
    int tx = threadIdx.x, ty = threadIdx.y;  // 32 x 8
#pragma unroll
    for (int i = 0; i < 4; i++)
        tile[ty + i * 8][tx] = in[(size_t)(r0 + ty + i * 8) * C + c0 + tx];
    __syncthreads();
#pragma unroll
    for (int i = 0; i < 4; i++)
        out[(size_t)(c0 + ty + i * 8) * R + r0 + tx] = f2bf(tile[tx][ty + i * 8]);
}

// W_h [1024][4096] fp32 -> fragment-ordered bf16 pack (K=1024: 32 ksteps)
__global__ void k_pack_wh(const float* __restrict__ Wh, unsigned short* __restrict__ out) {
    int gid = blockIdx.x * 256 + threadIdx.x;  // 524288 = 256 nfrag * 32 ks * 64 lane
    int lane = gid & 63, ks = (gid >> 6) & 31, nfrag = gid >> 11;
    int col = (nfrag & 3) * 1024 + ((nfrag >> 2) << 4) + (lane & 15);
    int kb = ks * 32 + ((lane >> 4) << 3);
    short8 v;
#pragma unroll
    for (int e = 0; e < 8; e++) v[e] = (short)f2bf(Wh[(size_t)(kb + e) * 4096 + col]);
    *reinterpret_cast<short8*>(out + (size_t)gid * 8) = v;
}

// W_in [768][4096] fp32 -> fragment-ordered bf16 pack (K=768: 24 ksteps)
__global__ void k_pack_win(const float* __restrict__ Win, unsigned short* __restrict__ out) {
    int gid = blockIdx.x * 256 + threadIdx.x;  // 393216 = 256 nfrag * 24 ks * 64 lane
    int lane = gid & 63;
    int comp = gid >> 6;           // nfrag*24 + ks
    int ks = comp % 24, nfrag = comp / 24;
    int col = (nfrag & 3) * 1024 + ((nfrag >> 2) << 4) + (lane & 15);
    int kb = ks * 32 + ((lane >> 4) << 3);
    short8 v;
#pragma unroll
    for (int e = 0; e < 8; e++) v[e] = (short)f2bf(Win[(size_t)(kb + e) * 4096 + col]);
    *reinterpret_cast<short8*>(out + (size_t)gid * 8) = v;
}

__global__ void k_bias(const float* __restrict__ bi, const float* __restrict__ bh, float* __restrict__ bs) {
    int i = blockIdx.x * 256 + threadIdx.x;
    if (i < 4096) bs[i] = bi[i] + bh[i];
}

// ---------------- generic bf16 GEMM: C[M][N] = A[M][K] * BT[N][K] ----------------
__global__ __launch_bounds__(256) void k_gemm_bf16(
    const unsigned short* __restrict__ A,
    const unsigned short* __restrict__ BT,
    unsigned short* __restrict__ C,
    int M, int N, int K)
{
    __shared__ unsigned short Asl[128 * 40];
    __shared__ unsigned short Bsl[128 * 40];
    int t = threadIdx.x, lane = t & 63, w = t >> 6;
    int m0 = blockIdx.y * 128, n0 = blockIdx.x * 128;
    int wm = (w >> 1) * 64, wn = (w & 1) * 64;
    float4_t acc[4][4] = {};

    for (int k0 = 0; k0 < K; k0 += 32) {
        __syncthreads();
#pragma unroll
        for (int p = 0; p < 2; p++) {
            int flat = p * 256 + t;
            int row = flat >> 2, kq = flat & 3;
            short8 va = *reinterpret_cast<const short8*>(A + (size_t)(m0 + row) * K + k0 + kq * 8);
            const short4_t* vp = reinterpret_cast<const short4_t*>(&va);
            *reinterpret_cast<short4_t*>(&Asl[row * 40 + kq * 8]) = vp[0];
            *reinterpret_cast<short4_t*>(&Asl[row * 40 + kq * 8 + 4]) = vp[1];
            short8 vb = *reinterpret_cast<const short8*>(BT + (size_t)(n0 + row) * K + k0 + kq * 8);
            const short4_t* wp = reinterpret_cast<const short4_t*>(&vb);
            *reinterpret_cast<short4_t*>(&Bsl[row * 40 + kq * 8]) = wp[0];
            *reinterpret_cast<short4_t*>(&Bsl[row * 40 + kq * 8 + 4]) = wp[1];
        }
        __syncthreads();
        short8 af[4], bfr[4];
#pragma unroll
        for (int mi = 0; mi < 4; mi++)
            af[mi] = ld_frag8(&Asl[(wm + mi * 16 + (lane & 15)) * 40 + (lane >> 4) * 8]);
#pragma unroll
        for (int ni = 0; ni < 4; ni++)
            bfr[ni] = ld_frag8(&Bsl[(wn + ni * 16 + (lane & 15)) * 40 + (lane >> 4) * 8]);
#pragma unroll
        for (int mi = 0; mi < 4; mi++)
#pragma unroll
            for (int ni = 0; ni < 4; ni++)
                acc[mi][ni] = __builtin_amdgcn_mfma_f32_16x16x32_bf16(af[mi], bfr[ni], acc[mi][ni], 0, 0, 0);
    }

#pragma unroll
    for (int mi = 0; mi < 4; mi++)
#pragma unroll
        for (int ni = 0; ni < 4; ni++)
#pragma unroll
            for (int r = 0; r < 4; r++) {
                int row = m0 + wm + mi * 16 + (lane >> 4) * 4 + r;
                int col = n0 + wn + ni * 16 + (lane & 15);
                C[(size_t)row * N + col] = f2bf(acc[mi][ni][r]);
            }
}

// ---------------- fused persistent LSTM scan (round-9 structure, trimmed) ----------------
// grid 256 = 64 unit-tiles x 4 batch-quarters; block 256 = 4 waves.
// Gate pre-act = x_t*Win + h_{t-1}*Wh + bias, unified K=768+1024 wave-split.
// Wh slice (128KB) in LDS; Win slice (4 gates x 6 ksteps x 16B = 96 VGPR) in regs.
// h exchange: round-7 protocol (sc0/sc1 IC ops, padded flags, wave-local poll).
// Trims vs round 9: x loads from PRE-CONVERTED bf16 text (no per-step f2bf x48,
// half the bytes); hs = normal L2 store (ack retires fast in next drain).
__global__ __launch_bounds__(256, 1) void k_scan(
    const unsigned short* __restrict__ textb,   // [64*512][768] bf16
    const unsigned short* __restrict__ WhPack,  // frag-ordered, 32 ksteps
    const unsigned short* __restrict__ WinPack, // frag-ordered, 24 ksteps
    const float* __restrict__ bias_sum,         // [4096]
    unsigned short* __restrict__ h_bufs,        // [2][64][1024] bf16
    unsigned short* __restrict__ hs,            // [64*512][1024] bf16
    unsigned int* __restrict__ flags)           // [256*16] padded arrival flags
{
    __shared__ unsigned short wlds[4 * 32 * 64 * 8];  // 128KB Wh slice
    __shared__ float part[4 * 4 * 16 * 17];           // 17KB partials

    int t = threadIdx.x, lane = t & 63, w = t >> 6;
    int bb = blockIdx.x;
    int ut = bb >> 2, mq = bb & 3;
    int u = lane & 15, lq = lane >> 4;
    int ml = t >> 4, u2 = t & 15;
    int brow_c = mq * 16 + ml;               // combine-owned batch row
    int jcol = ut * 16 + u2;                 // combine-owned hidden col
    int brow_a = mq * 16 + u;                // A-fragment batch row (lane-based)
    float c_reg = 0.f;
    float bsv[4];
#pragma unroll
    for (int g = 0; g < 4; g++) bsv[g] = bias_sum[g * 1024 + jcol];

    const unsigned int* myflag = &flags[((((w << 4) + lane) << 2) + mq) << 4];

    // ---- Win fragments -> registers: wave w covers x-ksteps [w*6, w*6+6) ----
    short8 wfx[4][6];
#pragma unroll
    for (int g = 0; g < 4; g++)
#pragma unroll
        for (int kk = 0; kk < 6; kk++)
            wfx[g][kk] = *reinterpret_cast<const short8*>(
                WinPack + (((size_t)((ut * 4 + g) * 24 + w * 6 + kk)) << 9) + lane * 8);

    // ---- Wh slice (contiguous 65536 ushorts) -> LDS ----
    const unsigned short* wsrc = WhPack + (size_t)ut * 65536;
#pragma unroll
    for (int i = 0; i < 32; i++) {
        int idx = (i * 256 + t) * 8;
        *reinterpret_cast<short8*>(&wlds[idx]) = *reinterpret_cast<const short8*>(wsrc + idx);
    }
    __syncthreads();

    // ---- x contribution for step 0 ----
    float4_t acc[4];
    {
        const unsigned short* tp = textb + (size_t)(brow_a * 512 + 0) * 768 + w * 192 + lq * 8;
#pragma unroll
        for (int g = 0; g < 4; g++) acc[g] = (float4_t){0.f, 0.f, 0.f, 0.f};
#pragma unroll
        for (int kk = 0; kk < 6; kk++) {
            short8 a = *reinterpret_cast<const short8*>(tp + kk * 32);
#pragma unroll
            for (int g = 0; g < 4; g++)
                acc[g] = __builtin_amdgcn_mfma_f32_16x16x32_bf16(a, wfx[g][kk], acc[g], 0, 0, 0);
        }
    }

    for (int ts = 0; ts < 512; ts++) {
        const unsigned short* h_in = h_bufs + (size_t)(ts & 1) * 65536;
        unsigned short* h_out = h_bufs + (size_t)((ts + 1) & 1) * 65536;

        // h loads via coherence point, one drain
        const unsigned short* abase = h_in + (brow_a << 10) + (lq << 3);
        float4_t araw[8];
#pragma unroll
        for (int kk = 0; kk < 8; kk++)
            araw[kk] = ld_b128_coh_raw(abase + (w * 8 + kk) * 32);
        asm volatile("s_waitcnt vmcnt(0)" ::: "memory");
        __builtin_amdgcn_sched_barrier(0);

        // h-MFMAs continue accumulating on top of the x contribution
#pragma unroll
        for (int kk = 0; kk < 8; kk++) {
            short8 a = __builtin_bit_cast(short8, araw[kk]);
#pragma unroll
            for (int g = 0; g < 4; g++) {
                short8 b = *reinterpret_cast<const short8*>(&wlds[((g * 32 + w * 8 + kk) * 64 + lane) * 8]);
                acc[g] = __builtin_amdgcn_mfma_f32_16x16x32_bf16(a, b, acc[g], 0, 0, 0);
            }
        }
#pragma unroll
        for (int g = 0; g < 4; g++)
#pragma unroll
            for (int r = 0; r < 4; r++)
                part[((w * 4 + g) * 16 + lq * 4 + r) * 17 + u] = acc[g][r];
        __syncthreads();

        // combine
        float gv[4];
#pragma unroll
        for (int g = 0; g < 4; g++) {
            float s = 0.f;
#pragma unroll
            for (int wv = 0; wv < 4; wv++) s += part[((wv * 4 + g) * 16 + ml) * 17 + u2];
            gv[g] = s + bsv[g];
        }
        float rt = sigm(gv[0]), ft = sigm(gv[1]), gt = tanh_fast(gv[2]), ot = sigm(gv[3]);
        c_reg = ft * c_reg + rt * gt;
        float hn = ot * tanh_fast(c_reg);
        unsigned short hb = f2bf(hn);
        st_b16_coh(&h_out[(brow_c << 10) + jcol], hb);

        if (ts != 511) {
            unsigned want = (unsigned)(ts + 1);
            __syncthreads();   // release drain: h sc1 stores ack'd at IC
            if (t == 0)
                __hip_atomic_store(&flags[bb * 16], want, __ATOMIC_RELAXED, __HIP_MEMORY_SCOPE_AGENT);
            hs[(((size_t)(brow_c * 512 + ts)) << 10) + jcol] = hb;  // normal L2 store (fast ack)

            // ---- x contribution for step ts+1 (bf16 loads, no conversion) ----
            {
                const unsigned short* tp = textb + (size_t)(brow_a * 512 + ts + 1) * 768 + w * 192 + lq * 8;
#pragma unroll
                for (int g = 0; g < 4; g++) acc[g] = (float4_t){0.f, 0.f, 0.f, 0.f};
#pragma unroll
                for (int kk = 0; kk < 6; kk++) {
                    short8 a = *reinterpret_cast<const short8*>(tp + kk * 32);
#pragma unroll
                    for (int g = 0; g < 4; g++)
                        acc[g] = __builtin_amdgcn_mfma_f32_16x16x32_bf16(a, wfx[g][kk], acc[g], 0, 0, 0);
                }
            }

            // wave-local poll: lanes 0..15 watch this wave's 16 producers
            if (lane < 16) {
                while (__hip_atomic_load(myflag, __ATOMIC_RELAXED, __HIP_MEMORY_SCOPE_AGENT) < want)
                    __builtin_amdgcn_s_sleep(1);
            }
            __builtin_amdgcn_sched_barrier(0);
        } else {
            hs[(((size_t)(brow_c * 512 + ts)) << 10) + jcol] = hb;
            __syncthreads();
        }
    }
}

// ---------------- tail kernels ----------------

__global__ void k_fh(const unsigned short* __restrict__ h, const float* __restrict__ Wlo,
                     const float* __restrict__ blo, float* __restrict__ fh) {
    int gid = blockIdx.x * 256 + threadIdx.x;  // 32768
    int b = gid >> 9, d = gid & 511;
    float acc = blo[d];
    for (int k = 0; k < 1024; k++) acc += bf2f(h[b * 1024 + k]) * Wlo[k * 512 + d];
    fh[gid] = acc;
}

__global__ void k_wsb(const float* __restrict__ fh, const float* __restrict__ Was,
                      const float* __restrict__ bas, float* __restrict__ WSb) {
    int gid = blockIdx.x * 256 + threadIdx.x;  // 16384
    int b = gid >> 8, v = gid & 255;
    float acc = bas[v];
    for (int k = 0; k < 512; k++) acc += fh[b * 512 + k] * Was[k * 256 + v];
    WSb[gid] = acc;
}

__global__ void k_score(const unsigned short* __restrict__ WH, const float* __restrict__ bah,
                        const float* __restrict__ WSb, const float* __restrict__ Wv,
                        const float* __restrict__ bv, float* __restrict__ score) {
    int row = blockIdx.x * 4 + (threadIdx.x >> 6);  // 32768 rows
    int lane = threadIdx.x & 63;
    int b = row >> 9;
    float acc = 0.f;
#pragma unroll
    for (int q = 0; q < 4; q++) {
        int v = q * 64 + lane;
        float val = bf2f(WH[(size_t)row * 256 + v]) + bah[v] + WSb[b * 256 + v];
        acc += tanhf(val) * Wv[v];
    }
#pragma unroll
    for (int o = 32; o; o >>= 1) acc += __shfl_down(acc, o);
    if (lane == 0) score[row] = acc + bv[0];
}

__global__ __launch_bounds__(512) void k_softmax(const float* __restrict__ score, float* __restrict__ attn) {
    __shared__ float red[8];
    __shared__ float red2[8];
    int b = blockIdx.x, t = threadIdx.x;
    float x = score[b * 512 + t];
    float m = x;
#pragma unroll
    for (int o = 32; o; o >>= 1) m = fmaxf(m, __shfl_xor(m, o));
    if ((t & 63) == 0) red[t >> 6] = m;
    __syncthreads();
    if (t == 0) { float mm = red[0]; for (int i = 1; i < 8; i++) mm = fmaxf(mm, red[i]); red[0] = mm; }
    __syncthreads();
    m = red[0];
    float e = __expf(x - m);
    float s = e;
#pragma unroll
    for (int o = 32; o; o >>= 1) s += __shfl_xor(s, o);
    if ((t & 63) == 0) red2[t >> 6] = s;
    __syncthreads();
    if (t == 0) { float ss = 0.f; for (int i = 0; i < 8; i++) ss += red2[i]; red2[0] = ss; }
    __syncthreads();
    attn[b * 512 + t] = e / red2[0];
}

__global__ void k_attnout(const unsigned short* __restrict__ hs, const float* __restrict__ attn,
                          float* __restrict__ ao) {
    __shared__ float a_s[512];
    int b = blockIdx.x >> 2;
    int hcol = (blockIdx.x & 3) * 256 + threadIdx.x;
    a_s[threadIdx.x] = attn[b * 512 + threadIdx.x];
    a_s[256 + threadIdx.x] = attn[b * 512 + 256 + threadIdx.x];
    __syncthreads();
    float acc = 0.f;
    for (int s = 0; s < 512; s++)
        acc += bf2f(hs[((size_t)(b * 512 + s)) * 1024 + hcol]) * a_s[s];
    ao[b * 1024 + hcol] = acc;
}

__global__ void k_out(const float* __restrict__ fh, const float* __restrict__ ao,
                      const float* __restrict__ Wout, const float* __restrict__ bout,
                      float* __restrict__ out) {
    int t = threadIdx.x;
    if (t >= 128) return;
    int b = t >> 1, o = t & 1;
    float acc = bout[o];
    for (int k = 0; k < 512; k++) acc += fh[b * 512 + k] * Wout[k * 2 + o];
    for (int k = 0; k < 1024; k++) acc += ao[b * 1024 + k] * Wout[(512 + k) * 2 + o];
    out[b * 2 + o] = sigm(acc);
}

// ---------------- launch ----------------

extern "C" void kernel_launch(void* const* d_in, const int* in_sizes, int n_in,
                              void* d_out, int out_size, void* d_ws, size_t ws_size,
                              hipStream_t stream) {
    const float* text  = (const float*)d_in[0];
    const float* W_in  = (const float*)d_in[1];
    const float* b_in  = (const float*)d_in[2];
    const float* W_h   = (const float*)d_in[3];
    const float* b_h   = (const float*)d_in[4];
    const float* W_ah  = (const float*)d_in[5];
    const float* b_ah  = (const float*)d_in[6];
    const float* W_as  = (const float*)d_in[7];
    const float* b_as  = (const float*)d_in[8];
    const float* W_v   = (const float*)d_in[9];
    const float* b_v   = (const float*)d_in[10];
    const float* W_lo  = (const float*)d_in[11];
    const float* b_lo  = (const float*)d_in[12];
    const float* W_out = (const float*)d_in[13];
    const float* b_out = (const float*)d_in[14];
    float* out = (float*)d_out;

    char* ws = (char*)d_ws;
    size_t off = 0;
    auto alloc = [&](size_t bytes) {
        void* p = ws + off;
        off = (off + bytes + 255) & ~(size_t)255;
        return p;
    };
    unsigned short* WhPack  = (unsigned short*)alloc((size_t)4096 * 1024 * 2);
    unsigned short* WinPack = (unsigned short*)alloc((size_t)4096 * 768 * 2);
    unsigned short* WahT    = (unsigned short*)alloc((size_t)256 * 1024 * 2);
    float*          biassum = (float*)alloc(4096 * 4);
    unsigned short* textb   = (unsigned short*)alloc((size_t)32768 * 768 * 2);
    unsigned short* hsbuf   = (unsigned short*)alloc((size_t)32768 * 1024 * 2);
    unsigned short* h_bf    = (unsigned short*)alloc((size_t)2 * 65536 * 2);
    unsigned short* WHb     = (unsigned short*)alloc((size_t)32768 * 256 * 2);
    float*          fh      = (float*)alloc(32768 * 4);
    float*          WSb     = (float*)alloc(16384 * 4);
    float*          score   = (float*)alloc(32768 * 4);
    float*          attn    = (float*)alloc(32768 * 4);
    float*          ao      = (float*)alloc(65536 * 4);
    unsigned int*   flags   = (unsigned int*)alloc(256 * 16 * 4);

    // prep
    dim3 tb(32, 8);
    k_transpose_bf16<<<dim3(256 / 32, 1024 / 32), tb, 0, stream>>>(W_ah, WahT, 1024, 256);
    k_pack_wh<<<2048, 256, 0, stream>>>(W_h, WhPack);
    k_pack_win<<<1536, 256, 0, stream>>>(W_in, WinPack);
    k_bias<<<16, 256, 0, stream>>>(b_in, b_h, biassum);
    k_f32_to_bf16<<<24576, 256, 0, stream>>>(text, textb, 32768 * 768);
    hipMemsetAsync(h_bf, 0, (size_t)2 * 65536 * 2, stream);
    hipMemsetAsync(flags, 0, 256 * 16 * 4, stream);

    // fused scan (single launch; input GEMM folded in, bf16 text)
    k_scan<<<256, 256, 0, stream>>>(textb, WhPack, WinPack, biassum, h_bf, hsbuf, flags);

    // tail (h after step 511 lives in buffer (512 & 1) == 0)
    k_fh<<<128, 256, 0, stream>>>(h_bf, W_lo, b_lo, fh);
    k_wsb<<<64, 256, 0, stream>>>(fh, W_as, b_as, WSb);
    k_gemm_bf16<<<dim3(2, 256), 256, 0, stream>>>(hsbuf, WahT, WHb, 32768, 256, 1024);
    k_score<<<8192, 256, 0, stream>>>(WHb, b_ah, WSb, W_v, b_v, score);
    k_softmax<<<64, 512, 0, stream>>>(score, attn);
    k_attnout<<<256, 256, 0, stream>>>(hsbuf, attn, ao);
    k_out<<<1, 128, 0, stream>>>(fh, ao, W_out, b_out, out);
}